// Round 8
// baseline (1542.100 us; speedup 1.0000x reference)
//
#include <hip/hip_runtime.h>
#include <cmath>

// Shapes: B=128, D=192, DEPTH=12, H=3(hd=64), E=4, N=65(tokens), NC=100, WIN_HALF=3
#define ROWS 8320
#define DD   192

typedef __attribute__((ext_vector_type(8))) _Float16 half8;
typedef __attribute__((ext_vector_type(4))) float floatx4;

#define GLD16(gp, lp) __builtin_amdgcn_global_load_lds( \
    (const __attribute__((address_space(1))) void*)(gp), \
    (__attribute__((address_space(3))) void*)(lp), 16, 0, 0)

#define MFMA_F16 __builtin_amdgcn_mfma_f32_16x16x32_f16

// exact gelu ONLY. (r2-r5 lesson): the top-2 expert gate flips on ~1e-4 systematic
// activation shifts (tanh-gelu approx -> 9.5e-2 discrete output error). ~1e-7-level
// fp32 reorder noise is empirically tolerated (atomicAdd ordering). Do NOT approximate.
__device__ __forceinline__ float gelu_f(float x) {
    return 0.5f * x * (1.0f + erff(x * 0.70710678118654752440f));
}

// block-wide sum for blockDim.x == 192 (embed only)
__device__ __forceinline__ float blk_sum_192(float v, float* sbuf) {
    int tid = threadIdx.x;
    sbuf[tid] = v;
    __syncthreads();
    for (int off = 96; off >= 3; off >>= 1) {
        if (tid < off) sbuf[tid] += sbuf[tid + off];
        __syncthreads();
    }
    float r = sbuf[0] + sbuf[1] + sbuf[2];
    __syncthreads();
    return r;
}

// ---------------- all weight conversions in ONE launch (data-identical to split) ------
__device__ __forceinline__ void cvt8(const float* __restrict__ sp, _Float16* __restrict__ dp) {
    #pragma unroll
    for (int j = 0; j < 8; j++) dp[j] = (_Float16)sp[j];
}

__global__ __launch_bounds__(256) void cvt_all_kernel(
    const float* __restrict__ qkv_w, const float* __restrict__ proj_w,
    const float* __restrict__ e_w1, const float* __restrict__ e_w2,
    _Float16* __restrict__ qkvw_h, _Float16* __restrict__ projw_h,
    _Float16* __restrict__ ew1_h, _Float16* __restrict__ ew2_h)
{
    long i = (long)blockIdx.x * 256 + threadIdx.x;
    const long n_qkv  = (long)12 * 576 * 192 / 8;    // 165888
    const long n_proj = (long)12 * 192 * 192 / 8;    // 55296
    const long n_w1   = (long)12 * 1536 * 192 / 8;   // 442368
    const long n_w2   = (long)12 * 192 * 192;        // 442368 perm items
    if (i < n_qkv) { cvt8(qkv_w + i * 8, qkvw_h + i * 8); return; }
    i -= n_qkv;
    if (i < n_proj) { cvt8(proj_w + i * 8, projw_h + i * 8); return; }
    i -= n_proj;
    if (i < n_w1) { cvt8(e_w1 + i * 8, ew1_h + i * 8); return; }
    i -= n_w1;
    if (i < n_w2) {
        // e_w2 (12,4,192,384) -> fp16 cat layout [l][n][K'=1536], col = e*384+k
        int l = (int)(i / (192 * 192));
        int rem = (int)(i % (192 * 192));
        int n = rem / 192, p = rem % 192;
        int c0 = p * 8;
        int e = c0 / 384, k0 = c0 % 384;
        cvt8(e_w2 + (((size_t)l * 4 + e) * 192 + n) * 384 + k0, ew2_h + i * 8);
    }
}

// ---------------- patch embed + LN + cls + pos (fp32) ----------------
__global__ __launch_bounds__(192) void embed_kernel(
    const float* __restrict__ x, const float* __restrict__ conv_w,
    const float* __restrict__ conv_b, const float* __restrict__ pe_g,
    const float* __restrict__ pe_b, const float* __restrict__ cls_tok,
    const float* __restrict__ pos, float* __restrict__ t)
{
    __shared__ float patch[48];
    __shared__ float red[192];
    int blk = blockIdx.x;
    int b = blk / 65, n = blk % 65;
    int tid = threadIdx.x;
    if (n == 0) {
        t[(size_t)b * 65 * DD + tid] = cls_tok[tid] + pos[tid];
        return;
    }
    int p = n - 1, gy = p / 8, gx = p % 8;
    if (tid < 48) {
        int c = tid / 16, iy = (tid % 16) / 4, ix = tid % 4;
        patch[tid] = x[((size_t)b * 3 + c) * 1024 + (size_t)(gy * 4 + iy) * 32 + (gx * 4 + ix)];
    }
    __syncthreads();
    float s = conv_b[tid];
    const float* w = conv_w + (size_t)tid * 48;
    #pragma unroll
    for (int f = 0; f < 48; f++) s += patch[f] * w[f];
    float mean = blk_sum_192(s, red) * (1.0f / 192.0f);
    float d = s - mean;
    float var = blk_sum_192(d * d, red) * (1.0f / 192.0f);
    float o = d * rsqrtf(var + 1e-5f) * pe_g[tid] + pe_b[tid];
    t[((size_t)b * 65 + n) * DD + tid] = o + pos[(size_t)n * DD + tid];
}

// ---------------- LayerNorm, wave-per-row (4 rows/block, shuffle-only) ----------------
__global__ __launch_bounds__(256) void ln_kernel(
    const float* __restrict__ in,
    float* __restrict__ yf, _Float16* __restrict__ yh,
    const float* __restrict__ g, const float* __restrict__ bb, long in_stride, int nrows,
    const float* __restrict__ gwm, const float* __restrict__ gb,
    int4* __restrict__ gwout)
{
    int wave = threadIdx.x >> 6, lane = threadIdx.x & 63;
    int r = blockIdx.x * 4 + wave;
    if (r >= nrows) return;
    const float* row = in + (size_t)r * in_stride;
    float v0 = row[lane], v1 = row[lane + 64], v2 = row[lane + 128];
    float s = v0 + v1 + v2;
    #pragma unroll
    for (int off = 32; off > 0; off >>= 1) s += __shfl_xor(s, off);
    float mean = s * (1.0f / 192.0f);
    float d0 = v0 - mean, d1 = v1 - mean, d2 = v2 - mean;
    float q = d0 * d0 + d1 * d1 + d2 * d2;
    #pragma unroll
    for (int off = 32; off > 0; off >>= 1) q += __shfl_xor(q, off);
    float rstd = rsqrtf(q * (1.0f / 192.0f) + 1e-5f);
    float o0 = d0 * rstd * g[lane] + bb[lane];
    float o1 = d1 * rstd * g[lane + 64] + bb[lane + 64];
    float o2 = d2 * rstd * g[lane + 128] + bb[lane + 128];
    if (yf) {
        float* yr = yf + (size_t)r * DD;
        yr[lane] = o0; yr[lane + 64] = o1; yr[lane + 128] = o2;
    }
    if (yh) {
        _Float16* yr = yh + (size_t)r * DD;
        yr[lane] = (_Float16)o0; yr[lane + 64] = (_Float16)o1; yr[lane + 128] = (_Float16)o2;
    }
    if (gwm) {
        float pe[4];
        #pragma unroll
        for (int e = 0; e < 4; e++) {
            const float* w = gwm + (size_t)e * DD;
            pe[e] = o0 * w[lane] + o1 * w[lane + 64] + o2 * w[lane + 128];
            #pragma unroll
            for (int off = 32; off > 0; off >>= 1) pe[e] += __shfl_xor(pe[e], off);
        }
        if (lane == 0) {
            #pragma unroll
            for (int e = 0; e < 4; e++) pe[e] += gb[e];
            float mx = fmaxf(fmaxf(pe[0], pe[1]), fmaxf(pe[2], pe[3]));
            float ex[4];
            #pragma unroll
            for (int e = 0; e < 4; e++) ex[e] = expf(pe[e] - mx);
            int i0 = 0;
            #pragma unroll
            for (int e = 1; e < 4; e++) if (ex[e] > ex[i0]) i0 = e;
            int i1 = (i0 == 0) ? 1 : 0;
            #pragma unroll
            for (int e = 0; e < 4; e++) if (e != i0 && ex[e] > ex[i1]) i1 = e;
            float denom = ex[i0] + ex[i1];
            int4 o4;
            o4.x = i0; o4.y = i1;
            o4.z = __float_as_int(ex[i0] / denom);
            o4.w = __float_as_int(ex[i1] / denom);
            gwout[r] = o4;
        }
    }
}

// ---------------- build per-expert row lists; entry = (row<<1)|rank ----------------
__global__ __launch_bounds__(256) void gate_build_kernel(
    const int4* __restrict__ gwrow, int* __restrict__ cnt,
    int* __restrict__ list, float* __restrict__ wlist, int rows)
{
    int r = blockIdx.x * 256 + threadIdx.x;
    int lane = threadIdx.x & 63;
    bool active = r < rows;
    int4 gv = active ? gwrow[r] : int4{-1, -1, 0, 0};
    #pragma unroll
    for (int e = 0; e < 4; e++) {
        bool sel = active && (gv.x == e || gv.y == e);
        int rank = (gv.x == e) ? 0 : 1;
        float w = (gv.x == e) ? __int_as_float(gv.z) : __int_as_float(gv.w);
        unsigned long long mask = __ballot(sel);
        int cw = __popcll(mask);
        if (cw) {
            int leader = __ffsll((long long)mask) - 1;
            int base = 0;
            if (lane == leader) base = atomicAdd(&cnt[e], cw);
            base = __shfl(base, leader);
            if (sel) {
                int idx = base + __popcll(mask & ((1ULL << lane) - 1ULL));
                list[(size_t)e * ROWS + idx] = (r << 1) | rank;
                wlist[(size_t)e * ROWS + idx] = w;
            }
        }
    }
}

// ---------------- fp16 MFMA GEMM, K=192 (round-1 verified dual-LDS form) --------------
// MODE 0: out fp16 packed [M][Nn]   (qkv; no bias)
// MODE 2: t[r*192+n] += scale[0]*(acc + bias[n])   (proj)
template <int MODE>
__global__ __launch_bounds__(256) void gemm_h(
    const _Float16* __restrict__ A, const _Float16* __restrict__ W,
    int Nn, _Float16* __restrict__ outH, float* __restrict__ t,
    const float* __restrict__ bias, const float* __restrict__ scale)
{
    __shared__ __align__(16) _Float16 As[64 * 192];   // 24KB
    __shared__ __align__(16) _Float16 Ws[64 * 192];   // 24KB
    const int tid = threadIdx.x;
    const int lane = tid & 63, wave = tid >> 6;
    const int m0 = blockIdx.x * 64, n0 = blockIdx.y * 64;
    const int wm = (wave & 1) * 32, wn = (wave >> 1) * 32;
    const int lr = lane & 15, quad = lane >> 4;

    #pragma unroll
    for (int i = 0; i < 6; i++) {
        int s = (wave * 6 + i) * 64 + lane;
        int rr = s / 24, c = s % 24;
        GLD16(A + (size_t)(m0 + rr) * 192 + (c ^ (rr & 7)) * 8,
              (char*)As + (size_t)(wave * 6 + i) * 1024);
        GLD16(W + (size_t)(n0 + rr) * 192 + (c ^ (rr & 7)) * 8,
              (char*)Ws + (size_t)(wave * 6 + i) * 1024);
    }
    __syncthreads();

    floatx4 zero = {0.f, 0.f, 0.f, 0.f};
    floatx4 acc[2][2];
    acc[0][0] = zero; acc[0][1] = zero; acc[1][0] = zero; acc[1][1] = zero;

    #pragma unroll
    for (int m = 0; m < 6; m++) {
        int ch = m * 4 + quad;
        half8 a[2], w[2];
        #pragma unroll
        for (int ti = 0; ti < 2; ti++) {
            int ar = wm + ti * 16 + lr;
            a[ti] = *(const half8*)(As + ((size_t)ar * 24 + (ch ^ (ar & 7))) * 8);
            int cr = wn + ti * 16 + lr;
            w[ti] = *(const half8*)(Ws + ((size_t)cr * 24 + (ch ^ (cr & 7))) * 8);
        }
        #pragma unroll
        for (int ti = 0; ti < 2; ti++)
            #pragma unroll
            for (int tj = 0; tj < 2; tj++)
                acc[ti][tj] = MFMA_F16(a[ti], w[tj], acc[ti][tj], 0, 0, 0);
    }

    float sc = (MODE == 2) ? scale[0] : 0.f;
    #pragma unroll
    for (int ti = 0; ti < 2; ti++)
        #pragma unroll
        for (int tj = 0; tj < 2; tj++)
            #pragma unroll
            for (int r = 0; r < 4; r++) {
                int grow = m0 + wm + ti * 16 + quad * 4 + r;
                int gcol = n0 + wn + tj * 16 + lr;
                float v = acc[ti][tj][r];
                if (MODE == 0) {
                    float vp = __shfl_xor(v, 1);
                    if ((lane & 1) == 0) {
                        union { _Float16 h[2]; unsigned u; } pk;
                        pk.h[0] = (_Float16)v;
                        pk.h[1] = (_Float16)vp;
                        *(unsigned*)(outH + (size_t)grow * Nn + (gcol & ~1)) = pk.u;
                    }
                } else {
                    t[(size_t)grow * DD + gcol] += sc * (v + bias[gcol]);
                }
            }
}

// ---------------- fused MoE v4: weights direct from L1/L2 to registers ----------------
// grid (260, 4): block = 32 gathered rows of expert e. 6 iters of 64 h-cols.
// No W1s/W2s LDS staging (weights are L1/L2-hot: 24KB W1 + 24KB W2 per iter).
// Fragment addresses are the composition of the old staging+read swizzles ->
// operand values BIT-IDENTICAL to the r1-verified kernel.
// LDS = 8KB (Hs double-buffer) -> occupancy wave-limited, 1 barrier/iter (was 2).
__global__ __launch_bounds__(256) void moe_kernel(
    const _Float16* __restrict__ yh, const _Float16* __restrict__ w1,
    const _Float16* __restrict__ w2, const float* __restrict__ b1,
    const float* __restrict__ b2, const float* __restrict__ scale,
    const int* __restrict__ cnt, const int* __restrict__ list,
    const float* __restrict__ wlist, float* __restrict__ t)
{
    __shared__ __align__(16) _Float16 Hs[2][32 * 64];   // 8KB
    const int e  = blockIdx.y;
    const int cnte = cnt[e];
    const int r0 = blockIdx.x * 32;
    if (r0 >= cnte) return;
    const int tid = threadIdx.x;
    const int lane = tid & 63, wave = tid >> 6;
    const int lr = lane & 15, quad = lane >> 4;
    const int wr = (wave & 1) * 16;
    const int wc1 = (wave >> 1) * 16;
    const int wc2 = (wave >> 1) * 96;

    // per-lane gather-list entry (lanes 16..63 replicate lanes 0..15's rows)
    int sl = r0 + wr + lr;
    int rv = -1; float wv = 0.f;
    if (sl < cnte) {
        rv = list[(size_t)e * ROWS + sl];
        wv = wlist[(size_t)e * ROWS + sl];
    }
    int arow = (rv >= 0) ? (rv >> 1) : 0;

    // A fragments straight to registers: row arow, chunk ch = m*4+quad
    half8 a[6];
    {
        const _Float16* ap = yh + (size_t)arow * 192 + quad * 8;
        #pragma unroll
        for (int m = 0; m < 6; m++) a[m] = *(const half8*)(ap + m * 32);
    }

    // per-output-row metadata (rows wr+quad*4+r handled by this lane's quad)
    int rvr[4]; float bwr[4];
    #pragma unroll
    for (int r = 0; r < 4; r++) {
        rvr[r] = __shfl(rv, quad * 4 + r);
        bwr[r] = __shfl(wv, quad * 4 + r);
    }

    const _Float16* w1e = w1 + (size_t)e * 384 * 192;

    floatx4 zero = {0.f, 0.f, 0.f, 0.f};
    floatx4 acc2[6];
    #pragma unroll
    for (int j = 0; j < 6; j++) acc2[j] = zero;

    int cur = 0;
    for (int nc = 0; nc < 6; nc++) {
        int ncg = e * 6 + nc;
        // gemm1: 32 rows x 64 hcols, K=192; A regs, W1 fragments direct from global.
        // quads of a 16-lane group read 4 contiguous 16B slices = one 64B line/row.
        floatx4 acc1[2];
        acc1[0] = zero; acc1[1] = zero;
        #pragma unroll
        for (int m = 0; m < 6; m++) {
            int ch = m * 4 + quad;
            #pragma unroll
            for (int tc = 0; tc < 2; tc++) {
                int cr = wc1 + tc * 32 + lr;
                half8 w = *(const half8*)(w1e + (size_t)(nc * 64 + cr) * 192 + ch * 8);
                acc1[tc] = MFMA_F16(a[m], w, acc1[tc], 0, 0, 0);
            }
        }
        // epilogue: gelu*w -> Hs[cur] fp16, packed 32-bit writes (XOR-banked)
        #pragma unroll
        for (int tc = 0; tc < 2; tc++)
            #pragma unroll
            for (int r = 0; r < 4; r++) {
                int hrow = wr + quad * 4 + r;
                int hcol = wc1 + tc * 32 + lr;
                float v = gelu_f(acc1[tc][r] + b1[64 * ncg + hcol]) * bwr[r];
                float vp = __shfl_xor(v, 1);
                if ((lane & 1) == 0) {
                    union { _Float16 h[2]; unsigned u; } pk;
                    pk.h[0] = (_Float16)v;
                    pk.h[1] = (_Float16)vp;
                    int cl = (hcol >> 3) ^ (hrow & 7);
                    *(unsigned*)(&Hs[cur][((size_t)hrow * 8 + cl) * 8 + (hcol & 7)]) = pk.u;
                }
            }
        __syncthreads();   // Hs[cur] visible; also fences Hs[cur] reuse 2 iters later
        // gemm2: out[32][192] partial, K=64; H from LDS, W2 fragments direct from global
        #pragma unroll
        for (int kk = 0; kk < 2; kk++) {
            int ar = wr + lr;
            int ch = kk * 4 + quad;
            half8 ha = *(const half8*)(&Hs[cur][((size_t)ar * 8 + (ch ^ (ar & 7))) * 8]);
            #pragma unroll
            for (int tj = 0; tj < 6; tj++) {
                int cr = wc2 + tj * 16 + lr;
                half8 w = *(const half8*)(w2 + (size_t)cr * 1536 + ncg * 64 + ch * 8);
                acc2[tj] = MFMA_F16(ha, w, acc2[tj], 0, 0, 0);
            }
        }
        cur ^= 1;
    }

    float sc = scale[0];
    #pragma unroll
    for (int tj = 0; tj < 6; tj++) {
        int gcol = wc2 + tj * 16 + lr;
        float b2v = b2[e * 192 + gcol];
        #pragma unroll
        for (int r = 0; r < 4; r++) {
            if (rvr[r] >= 0) {
                float v = sc * (acc2[tj][r] + bwr[r] * b2v);
                atomicAdd(&t[(size_t)(rvr[r] >> 1) * DD + gcol], v);
            }
        }
    }
}

// ---------------- banded attention v2: all-thread score phase, float2 LDS -------------
// (correctness-verified in r6/r7 with baseline-identical absmax; -45us vs v1)
__global__ __launch_bounds__(256) void attn_kernel(
    const _Float16* __restrict__ qkv, const float* __restrict__ temp,
    _Float16* __restrict__ o)
{
    __shared__ float q[65][66], k[65][66], v[65][66];
    __shared__ float p[65][9];
    int bh = blockIdx.x;
    int b = bh / 3, h = bh % 3;
    int tid = threadIdx.x;
    float coef = 0.125f / temp[h];
    const _Float16* base = qkv + (size_t)b * 65 * 576 + h * 64;
    for (int idx = tid; idx < 65 * 32; idx += 256) {
        int i = idx >> 5, d2 = (idx & 31) * 2;
        const _Float16* bp = base + (size_t)i * 576 + d2;
        q[i][d2] = (float)bp[0];   q[i][d2 + 1] = (float)bp[1];
        k[i][d2] = (float)bp[192]; k[i][d2 + 1] = (float)bp[193];
        v[i][d2] = (float)bp[384]; v[i][d2 + 1] = (float)bp[385];
    }
    __syncthreads();
    // scores: 455 (i,jo) work items spread over all 256 threads
    for (int idx = tid; idx < 65 * 7; idx += 256) {
        int i = idx / 7, jo = idx % 7;
        int j = i - 3 + jo;
        float s = -1e30f;
        if (j >= 0 && j < 65) {
            const float2* qr = (const float2*)&q[i][0];
            const float2* kr = (const float2*)&k[j][0];
            float acc = 0.f;
            #pragma unroll
            for (int d2 = 0; d2 < 32; d2++) {
                float2 aa = qr[d2], bb = kr[d2];
                acc += aa.x * bb.x + aa.y * bb.y;
            }
            s = acc * coef;
        }
        p[i][jo] = s;
    }
    __syncthreads();
    if (tid < 65) {
        float mx = -1e30f;
        #pragma unroll
        for (int jo = 0; jo < 7; jo++) mx = fmaxf(mx, p[tid][jo]);
        float ex[7], sum = 0.f;
        #pragma unroll
        for (int jo = 0; jo < 7; jo++) { ex[jo] = expf(p[tid][jo] - mx); sum += ex[jo]; }
        float inv = 1.0f / sum;
        #pragma unroll
        for (int jo = 0; jo < 7; jo++) p[tid][jo] = ex[jo] * inv;
    }
    __syncthreads();
    for (int idx = tid; idx < 65 * 32; idx += 256) {
        int i = idx >> 5, d2 = (idx & 31) * 2;
        float s0 = 0.f, s1 = 0.f;
        #pragma unroll
        for (int jo = 0; jo < 7; jo++) {
            int j = i - 3 + jo;
            if (j >= 0 && j < 65) {
                float pv = p[i][jo];
                s0 += pv * v[j][d2];
                s1 += pv * v[j][d2 + 1];
            }
        }
        union { _Float16 h2[2]; unsigned u; } pk;
        pk.h2[0] = (_Float16)s0; pk.h2[1] = (_Float16)s1;
        *(unsigned*)(o + ((size_t)b * 65 + i) * 192 + h * 64 + d2) = pk.u;
    }
}

// ---------------- hyper head (fp32) ----------------
__global__ __launch_bounds__(128) void head_kernel(
    const float* __restrict__ cls, const float* __restrict__ hc_w,
    const float* __restrict__ hc_b, const float* __restrict__ head_w,
    const float* __restrict__ head_b, float* __restrict__ out)
{
    __shared__ float c[192];
    __shared__ float hh[384];
    int b = blockIdx.x, tid = threadIdx.x;
    for (int i = tid; i < 192; i += 128) c[i] = cls[(size_t)b * 192 + i];
    __syncthreads();
    for (int i = tid; i < 384; i += 128) {
        int kx = i / 96, o = i % 96;
        float s = hc_b[i];
        #pragma unroll
        for (int j = 0; j < 4; j++) {
            int pp = (kx - j + 4) & 3;
            const float* w = hc_w + ((size_t)pp * 96 + o) * 48;
            const float* xv = c + j * 48;
            #pragma unroll
            for (int cc = 0; cc < 48; cc++) s += xv[cc] * w[cc];
        }
        hh[i] = gelu_f(s);
    }
    __syncthreads();
    for (int i = tid; i < 100; i += 128) {
        float s = head_b[i];
        const float* w = head_w + (size_t)i * 384;
        for (int kk = 0; kk < 384; kk++) s += hh[kk] * w[kk];
        out[(size_t)b * 100 + i] = s;
    }
}

extern "C" void kernel_launch(void* const* d_in, const int* in_sizes, int n_in,
                              void* d_out, int out_size, void* d_ws, size_t ws_size,
                              hipStream_t stream)
{
    const float* x        = (const float*)d_in[0];
    const float* conv_w   = (const float*)d_in[1];
    const float* conv_b   = (const float*)d_in[2];
    const float* pe_g     = (const float*)d_in[3];
    const float* pe_b     = (const float*)d_in[4];
    const float* cls_tok  = (const float*)d_in[5];
    const float* pos      = (const float*)d_in[6];
    const float* n1_g     = (const float*)d_in[7];
    const float* n1_b     = (const float*)d_in[8];
    const float* qkv_w    = (const float*)d_in[9];
    const float* temp     = (const float*)d_in[10];
    const float* proj_w   = (const float*)d_in[11];
    const float* proj_b   = (const float*)d_in[12];
    const float* n2_g     = (const float*)d_in[13];
    const float* n2_b     = (const float*)d_in[14];
    const float* gate_w   = (const float*)d_in[15];
    const float* gate_b   = (const float*)d_in[16];
    const float* e_w1     = (const float*)d_in[17];
    const float* e_b1     = (const float*)d_in[18];
    const float* e_w2     = (const float*)d_in[19];
    const float* e_b2     = (const float*)d_in[20];
    const float* attn_sc  = (const float*)d_in[21];
    const float* mlp_sc   = (const float*)d_in[22];
    const float* norm_g   = (const float*)d_in[23];
    const float* norm_b   = (const float*)d_in[24];
    const float* hc_w     = (const float*)d_in[25];
    const float* hc_b     = (const float*)d_in[26];
    const float* head_w   = (const float*)d_in[27];
    const float* head_b   = (const float*)d_in[28];

    // ---- ws layout ----
    char* base = (char*)d_ws;
    float*  t     = (float*)base;   base += (size_t)ROWS * DD * 4;        // 6.39MB
    int4*   gwrow = (int4*)base;    base += (size_t)ROWS * 16;            // 133KB
    int*    cnts  = (int*)base;     base += (size_t)12 * 4 * sizeof(int) + 64;
    int*    elist = (int*)base;     base += (size_t)4 * ROWS * 4;         // 133KB
    float*  ewls  = (float*)base;   base += (size_t)4 * ROWS * 4;         // 133KB
    float*  ycls  = (float*)base;   base += (size_t)128 * DD * 4;         // 98KB
    _Float16* yhb = (_Float16*)base; base += (size_t)ROWS * DD * 2;       // 3.19MB
    _Float16* qkvh = (_Float16*)base; base += (size_t)ROWS * 576 * 2;     // 9.58MB
    _Float16* osph = (_Float16*)base; base += (size_t)ROWS * DD * 2;      // 3.19MB
    _Float16* qkvw_h = (_Float16*)base; base += (size_t)12 * 576 * 192 * 2;  // 2.65MB
    _Float16* projw_h = (_Float16*)base; base += (size_t)12 * 192 * 192 * 2; // 0.88MB
    _Float16* ew1_h = (_Float16*)base; base += (size_t)12 * 1536 * 192 * 2;  // 7.1MB
    _Float16* ew2_h = (_Float16*)base; base += (size_t)12 * 192 * 1536 * 2;  // 7.1MB

    hipMemsetAsync(cnts, 0, 12 * 4 * sizeof(int), stream);

    // ---- all weight conversions, one launch ----
    {
        long total = (long)12 * 576 * 192 / 8 + (long)12 * 192 * 192 / 8
                   + (long)12 * 1536 * 192 / 8 + (long)12 * 192 * 192;
        cvt_all_kernel<<<(int)((total + 255) / 256), 256, 0, stream>>>(
            qkv_w, proj_w, e_w1, e_w2, qkvw_h, projw_h, ew1_h, ew2_h);
    }

    embed_kernel<<<128 * 65, 192, 0, stream>>>(x, conv_w, conv_b, pe_g, pe_b, cls_tok, pos, t);

    for (int l = 0; l < 12; l++) {
        ln_kernel<<<ROWS / 4, 256, 0, stream>>>(
            t, nullptr, yhb, n1_g + l * DD, n1_b + l * DD, DD, ROWS,
            nullptr, nullptr, nullptr);
        gemm_h<0><<<dim3(130, 9), 256, 0, stream>>>(
            yhb, qkvw_h + (size_t)l * 576 * 192, 576, qkvh, nullptr, nullptr, nullptr);
        attn_kernel<<<128 * 3, 256, 0, stream>>>(qkvh, temp + l * 3, osph);
        gemm_h<2><<<dim3(130, 3), 256, 0, stream>>>(
            osph, projw_h + (size_t)l * 192 * 192, 192, nullptr, t,
            proj_b + l * DD, attn_sc + l);
        ln_kernel<<<ROWS / 4, 256, 0, stream>>>(
            t, nullptr, yhb, n2_g + l * DD, n2_b + l * DD, DD, ROWS,
            gate_w + (size_t)l * 4 * DD, gate_b + l * 4, gwrow);
        gate_build_kernel<<<(ROWS + 255) / 256, 256, 0, stream>>>(
            gwrow, cnts + l * 4, elist, ewls, ROWS);
        moe_kernel<<<dim3(260, 4), 256, 0, stream>>>(
            yhb, ew1_h + (size_t)l * 1536 * 192, ew2_h + (size_t)l * 192 * 1536,
            e_b1 + (size_t)l * 1536, e_b2 + (size_t)l * 4 * 192, mlp_sc + l,
            cnts + l * 4, elist, ewls, t);
    }

    ln_kernel<<<32, 256, 0, stream>>>(
        t, ycls, nullptr, norm_g, norm_b, (long)65 * DD, 128,
        nullptr, nullptr, nullptr);
    head_kernel<<<128, 128, 0, stream>>>(ycls, hc_w, hc_b, head_w, head_b, (float*)d_out);
}

// Round 9
// 1289.028 us; speedup vs baseline: 1.1963x; 1.1963x over previous
//
#include <hip/hip_runtime.h>
#include <cmath>

// Shapes: B=128, D=192, DEPTH=12, H=3(hd=64), E=4, N=65(tokens), NC=100, WIN_HALF=3
#define ROWS 8320
#define DD   192

typedef __attribute__((ext_vector_type(8))) _Float16 half8;
typedef __attribute__((ext_vector_type(4))) float floatx4;

#define GLD16(gp, lp) __builtin_amdgcn_global_load_lds( \
    (const __attribute__((address_space(1))) void*)(gp), \
    (__attribute__((address_space(3))) void*)(lp), 16, 0, 0)

#define MFMA_F16 __builtin_amdgcn_mfma_f32_16x16x32_f16

// exact gelu ONLY. (r2-r5 lesson): the top-2 expert gate flips on ~1e-4 systematic
// activation shifts (tanh-gelu approx -> 9.5e-2 discrete output error). Do NOT approximate.
// (r8 lesson): weight fragments must be read via coalesced GLD16->LDS staging; direct
// per-lane column-strided global reads fan out to 64 cache lines per instruction.
__device__ __forceinline__ float gelu_f(float x) {
    return 0.5f * x * (1.0f + erff(x * 0.70710678118654752440f));
}

// block-wide sum for blockDim.x == 192 (embed only)
__device__ __forceinline__ float blk_sum_192(float v, float* sbuf) {
    int tid = threadIdx.x;
    sbuf[tid] = v;
    __syncthreads();
    for (int off = 96; off >= 3; off >>= 1) {
        if (tid < off) sbuf[tid] += sbuf[tid + off];
        __syncthreads();
    }
    float r = sbuf[0] + sbuf[1] + sbuf[2];
    __syncthreads();
    return r;
}

// ---------------- all weight conversions in ONE launch (data-identical to split) ------
__device__ __forceinline__ void cvt8(const float* __restrict__ sp, _Float16* __restrict__ dp) {
    #pragma unroll
    for (int j = 0; j < 8; j++) dp[j] = (_Float16)sp[j];
}

__global__ __launch_bounds__(256) void cvt_all_kernel(
    const float* __restrict__ qkv_w, const float* __restrict__ proj_w,
    const float* __restrict__ e_w1, const float* __restrict__ e_w2,
    _Float16* __restrict__ qkvw_h, _Float16* __restrict__ projw_h,
    _Float16* __restrict__ ew1_h, _Float16* __restrict__ ew2_h)
{
    long i = (long)blockIdx.x * 256 + threadIdx.x;
    const long n_qkv  = (long)12 * 576 * 192 / 8;    // 165888
    const long n_proj = (long)12 * 192 * 192 / 8;    // 55296
    const long n_w1   = (long)12 * 1536 * 192 / 8;   // 442368
    const long n_w2   = (long)12 * 192 * 192;        // 442368 perm items
    if (i < n_qkv) { cvt8(qkv_w + i * 8, qkvw_h + i * 8); return; }
    i -= n_qkv;
    if (i < n_proj) { cvt8(proj_w + i * 8, projw_h + i * 8); return; }
    i -= n_proj;
    if (i < n_w1) { cvt8(e_w1 + i * 8, ew1_h + i * 8); return; }
    i -= n_w1;
    if (i < n_w2) {
        // e_w2 (12,4,192,384) -> fp16 cat layout [l][n][K'=1536], col = e*384+k
        int l = (int)(i / (192 * 192));
        int rem = (int)(i % (192 * 192));
        int n = rem / 192, p = rem % 192;
        int c0 = p * 8;
        int e = c0 / 384, k0 = c0 % 384;
        cvt8(e_w2 + (((size_t)l * 4 + e) * 192 + n) * 384 + k0, ew2_h + i * 8);
    }
}

// ---------------- patch embed + LN + cls + pos (fp32) ----------------
__global__ __launch_bounds__(192) void embed_kernel(
    const float* __restrict__ x, const float* __restrict__ conv_w,
    const float* __restrict__ conv_b, const float* __restrict__ pe_g,
    const float* __restrict__ pe_b, const float* __restrict__ cls_tok,
    const float* __restrict__ pos, float* __restrict__ t)
{
    __shared__ float patch[48];
    __shared__ float red[192];
    int blk = blockIdx.x;
    int b = blk / 65, n = blk % 65;
    int tid = threadIdx.x;
    if (n == 0) {
        t[(size_t)b * 65 * DD + tid] = cls_tok[tid] + pos[tid];
        return;
    }
    int p = n - 1, gy = p / 8, gx = p % 8;
    if (tid < 48) {
        int c = tid / 16, iy = (tid % 16) / 4, ix = tid % 4;
        patch[tid] = x[((size_t)b * 3 + c) * 1024 + (size_t)(gy * 4 + iy) * 32 + (gx * 4 + ix)];
    }
    __syncthreads();
    float s = conv_b[tid];
    const float* w = conv_w + (size_t)tid * 48;
    #pragma unroll
    for (int f = 0; f < 48; f++) s += patch[f] * w[f];
    float mean = blk_sum_192(s, red) * (1.0f / 192.0f);
    float d = s - mean;
    float var = blk_sum_192(d * d, red) * (1.0f / 192.0f);
    float o = d * rsqrtf(var + 1e-5f) * pe_g[tid] + pe_b[tid];
    t[((size_t)b * 65 + n) * DD + tid] = o + pos[(size_t)n * DD + tid];
}

// ---------------- LayerNorm, wave-per-row (4 rows/block, shuffle-only) ----------------
__global__ __launch_bounds__(256) void ln_kernel(
    const float* __restrict__ in,
    float* __restrict__ yf, _Float16* __restrict__ yh,
    const float* __restrict__ g, const float* __restrict__ bb, long in_stride, int nrows,
    const float* __restrict__ gwm, const float* __restrict__ gb,
    int4* __restrict__ gwout)
{
    int wave = threadIdx.x >> 6, lane = threadIdx.x & 63;
    int r = blockIdx.x * 4 + wave;
    if (r >= nrows) return;
    const float* row = in + (size_t)r * in_stride;
    float v0 = row[lane], v1 = row[lane + 64], v2 = row[lane + 128];
    float s = v0 + v1 + v2;
    #pragma unroll
    for (int off = 32; off > 0; off >>= 1) s += __shfl_xor(s, off);
    float mean = s * (1.0f / 192.0f);
    float d0 = v0 - mean, d1 = v1 - mean, d2 = v2 - mean;
    float q = d0 * d0 + d1 * d1 + d2 * d2;
    #pragma unroll
    for (int off = 32; off > 0; off >>= 1) q += __shfl_xor(q, off);
    float rstd = rsqrtf(q * (1.0f / 192.0f) + 1e-5f);
    float o0 = d0 * rstd * g[lane] + bb[lane];
    float o1 = d1 * rstd * g[lane + 64] + bb[lane + 64];
    float o2 = d2 * rstd * g[lane + 128] + bb[lane + 128];
    if (yf) {
        float* yr = yf + (size_t)r * DD;
        yr[lane] = o0; yr[lane + 64] = o1; yr[lane + 128] = o2;
    }
    if (yh) {
        _Float16* yr = yh + (size_t)r * DD;
        yr[lane] = (_Float16)o0; yr[lane + 64] = (_Float16)o1; yr[lane + 128] = (_Float16)o2;
    }
    if (gwm) {
        float pe[4];
        #pragma unroll
        for (int e = 0; e < 4; e++) {
            const float* w = gwm + (size_t)e * DD;
            pe[e] = o0 * w[lane] + o1 * w[lane + 64] + o2 * w[lane + 128];
            #pragma unroll
            for (int off = 32; off > 0; off >>= 1) pe[e] += __shfl_xor(pe[e], off);
        }
        if (lane == 0) {
            #pragma unroll
            for (int e = 0; e < 4; e++) pe[e] += gb[e];
            float mx = fmaxf(fmaxf(pe[0], pe[1]), fmaxf(pe[2], pe[3]));
            float ex[4];
            #pragma unroll
            for (int e = 0; e < 4; e++) ex[e] = expf(pe[e] - mx);
            int i0 = 0;
            #pragma unroll
            for (int e = 1; e < 4; e++) if (ex[e] > ex[i0]) i0 = e;
            int i1 = (i0 == 0) ? 1 : 0;
            #pragma unroll
            for (int e = 0; e < 4; e++) if (e != i0 && ex[e] > ex[i1]) i1 = e;
            float denom = ex[i0] + ex[i1];
            int4 o4;
            o4.x = i0; o4.y = i1;
            o4.z = __float_as_int(ex[i0] / denom);
            o4.w = __float_as_int(ex[i1] / denom);
            gwout[r] = o4;
        }
    }
}

// ---------------- build per-expert row lists; entry = (row<<1)|rank ----------------
__global__ __launch_bounds__(256) void gate_build_kernel(
    const int4* __restrict__ gwrow, int* __restrict__ cnt,
    int* __restrict__ list, float* __restrict__ wlist, int rows)
{
    int r = blockIdx.x * 256 + threadIdx.x;
    int lane = threadIdx.x & 63;
    bool active = r < rows;
    int4 gv = active ? gwrow[r] : int4{-1, -1, 0, 0};
    #pragma unroll
    for (int e = 0; e < 4; e++) {
        bool sel = active && (gv.x == e || gv.y == e);
        int rank = (gv.x == e) ? 0 : 1;
        float w = (gv.x == e) ? __int_as_float(gv.z) : __int_as_float(gv.w);
        unsigned long long mask = __ballot(sel);
        int cw = __popcll(mask);
        if (cw) {
            int leader = __ffsll((long long)mask) - 1;
            int base = 0;
            if (lane == leader) base = atomicAdd(&cnt[e], cw);
            base = __shfl(base, leader);
            if (sel) {
                int idx = base + __popcll(mask & ((1ULL << lane) - 1ULL));
                list[(size_t)e * ROWS + idx] = (r << 1) | rank;
                wlist[(size_t)e * ROWS + idx] = w;
            }
        }
    }
}

// ---------------- fp16 MFMA GEMM, K=192 (round-1 verified dual-LDS form) --------------
// MODE 0: out fp16 packed [M][Nn]   (qkv; no bias)
// MODE 2: t[r*192+n] += scale[0]*(acc + bias[n])   (proj)
template <int MODE>
__global__ __launch_bounds__(256) void gemm_h(
    const _Float16* __restrict__ A, const _Float16* __restrict__ W,
    int Nn, _Float16* __restrict__ outH, float* __restrict__ t,
    const float* __restrict__ bias, const float* __restrict__ scale)
{
    __shared__ __align__(16) _Float16 As[64 * 192];   // 24KB
    __shared__ __align__(16) _Float16 Ws[64 * 192];   // 24KB
    const int tid = threadIdx.x;
    const int lane = tid & 63, wave = tid >> 6;
    const int m0 = blockIdx.x * 64, n0 = blockIdx.y * 64;
    const int wm = (wave & 1) * 32, wn = (wave >> 1) * 32;
    const int lr = lane & 15, quad = lane >> 4;

    #pragma unroll
    for (int i = 0; i < 6; i++) {
        int s = (wave * 6 + i) * 64 + lane;
        int rr = s / 24, c = s % 24;
        GLD16(A + (size_t)(m0 + rr) * 192 + (c ^ (rr & 7)) * 8,
              (char*)As + (size_t)(wave * 6 + i) * 1024);
        GLD16(W + (size_t)(n0 + rr) * 192 + (c ^ (rr & 7)) * 8,
              (char*)Ws + (size_t)(wave * 6 + i) * 1024);
    }
    __syncthreads();

    floatx4 zero = {0.f, 0.f, 0.f, 0.f};
    floatx4 acc[2][2];
    acc[0][0] = zero; acc[0][1] = zero; acc[1][0] = zero; acc[1][1] = zero;

    #pragma unroll
    for (int m = 0; m < 6; m++) {
        int ch = m * 4 + quad;
        half8 a[2], w[2];
        #pragma unroll
        for (int ti = 0; ti < 2; ti++) {
            int ar = wm + ti * 16 + lr;
            a[ti] = *(const half8*)(As + ((size_t)ar * 24 + (ch ^ (ar & 7))) * 8);
            int cr = wn + ti * 16 + lr;
            w[ti] = *(const half8*)(Ws + ((size_t)cr * 24 + (ch ^ (cr & 7))) * 8);
        }
        #pragma unroll
        for (int ti = 0; ti < 2; ti++)
            #pragma unroll
            for (int tj = 0; tj < 2; tj++)
                acc[ti][tj] = MFMA_F16(a[ti], w[tj], acc[ti][tj], 0, 0, 0);
    }

    float sc = (MODE == 2) ? scale[0] : 0.f;
    #pragma unroll
    for (int ti = 0; ti < 2; ti++)
        #pragma unroll
        for (int tj = 0; tj < 2; tj++)
            #pragma unroll
            for (int r = 0; r < 4; r++) {
                int grow = m0 + wm + ti * 16 + quad * 4 + r;
                int gcol = n0 + wn + tj * 16 + lr;
                float v = acc[ti][tj][r];
                if (MODE == 0) {
                    float vp = __shfl_xor(v, 1);
                    if ((lane & 1) == 0) {
                        union { _Float16 h[2]; unsigned u; } pk;
                        pk.h[0] = (_Float16)v;
                        pk.h[1] = (_Float16)vp;
                        *(unsigned*)(outH + (size_t)grow * Nn + (gcol & ~1)) = pk.u;
                    }
                } else {
                    t[(size_t)grow * DD + gcol] += sc * (v + bias[gcol]);
                }
            }
}

// ---------------- fused MoE v5: 64 rows/block, LDS-staged weights (r8 lesson) ---------
// grid (130, 4): block = 64 gathered rows of expert e. 6 iters of 64 h-cols.
// Per-block staging traffic unchanged -> per-ROW staging halves; blocks 520 -> 260.
// Wave w owns rows [w*16, w*16+16): gemm1 all 64 hcols (acc1[4]), gemm2 all 192
// out-cols (acc2[12]). All LDS layouts/XOR formulas identical to the r1-verified form.
// LDS = 24 + 24 + 8 = 56KB.
__global__ __launch_bounds__(256) void moe_kernel(
    const _Float16* __restrict__ yh, const _Float16* __restrict__ w1,
    const _Float16* __restrict__ w2, const float* __restrict__ b1,
    const float* __restrict__ b2, const float* __restrict__ scale,
    const int* __restrict__ cnt, const int* __restrict__ list,
    const float* __restrict__ wlist, float* __restrict__ t)
{
    __shared__ __align__(16) _Float16 W1s[64 * 192];  // 24KB
    __shared__ __align__(16) _Float16 W2s[192 * 64];  // 24KB
    __shared__ __align__(16) _Float16 Hs[64 * 64];    // 8KB
    const int e  = blockIdx.y;
    const int cnte = cnt[e];
    const int r0 = blockIdx.x * 64;
    if (r0 >= cnte) return;
    const int tid = threadIdx.x;
    const int lane = tid & 63, wave = tid >> 6;
    const int lr = lane & 15, quad = lane >> 4;
    const int wr = wave * 16;          // each wave owns 16 distinct rows

    // issue W1 chunk0 staging first (no dependencies)
    #pragma unroll
    for (int i = 0; i < 6; i++) {
        int s = (wave * 6 + i) * 64 + lane;
        int rr = s / 24, c = s % 24;
        GLD16(w1 + ((size_t)e * 384 + rr) * 192 + (c ^ (rr & 7)) * 8,
              (char*)W1s + (size_t)(wave * 6 + i) * 1024);
    }

    // per-lane gather-list entry (lanes 16..63 replicate lanes 0..15's rows)
    int sl = r0 + wr + lr;
    int rv = -1; float wv = 0.f;
    if (sl < cnte) {
        rv = list[(size_t)e * ROWS + sl];
        wv = wlist[(size_t)e * ROWS + sl];
    }
    int arow = (rv >= 0) ? (rv >> 1) : 0;

    // A fragments straight to registers: row arow, chunk ch = m*4+quad
    half8 a[6];
    {
        const _Float16* ap = yh + (size_t)arow * 192 + quad * 8;
        #pragma unroll
        for (int m = 0; m < 6; m++) a[m] = *(const half8*)(ap + m * 32);
    }

    // per-output-row metadata (rows wr+quad*4+r handled by this lane's quad)
    int rvr[4]; float bwr[4];
    #pragma unroll
    for (int r = 0; r < 4; r++) {
        rvr[r] = __shfl(rv, quad * 4 + r);
        bwr[r] = __shfl(wv, quad * 4 + r);
    }

    __syncthreads();   // W1[0] resident (vmcnt0 + barrier)

    floatx4 zero = {0.f, 0.f, 0.f, 0.f};
    floatx4 acc2[12];
    #pragma unroll
    for (int j = 0; j < 12; j++) acc2[j] = zero;

    for (int nc = 0; nc < 6; nc++) {
        int ncg = e * 6 + nc;
        // issue W2[ncg] (flies during gemm1)
        #pragma unroll
        for (int i = 0; i < 6; i++) {
            int s = (wave * 6 + i) * 64 + lane;
            int n = s >> 3, c = s & 7;
            GLD16(w2 + (size_t)n * 1536 + (ncg * 8 + (c ^ (n & 7))) * 8,
                  (char*)W2s + (size_t)(wave * 6 + i) * 1024);
        }
        // gemm1: this wave's 16 rows x all 64 hcols, K=192
        floatx4 acc1[4];
        #pragma unroll
        for (int tc = 0; tc < 4; tc++) acc1[tc] = zero;
        #pragma unroll
        for (int m = 0; m < 6; m++) {
            int ch = m * 4 + quad;
            #pragma unroll
            for (int tc = 0; tc < 4; tc++) {
                int cr = tc * 16 + lr;
                half8 w = *(const half8*)(W1s + ((size_t)cr * 24 + (ch ^ (cr & 7))) * 8);
                acc1[tc] = MFMA_F16(a[m], w, acc1[tc], 0, 0, 0);
            }
        }
        // epilogue: gelu*w -> Hs fp16, packed 32-bit writes (XOR-banked)
        #pragma unroll
        for (int tc = 0; tc < 4; tc++)
            #pragma unroll
            for (int r = 0; r < 4; r++) {
                int hrow = wr + quad * 4 + r;
                int hcol = tc * 16 + lr;
                float v = gelu_f(acc1[tc][r] + b1[64 * ncg + hcol]) * bwr[r];
                float vp = __shfl_xor(v, 1);
                if ((lane & 1) == 0) {
                    union { _Float16 h[2]; unsigned u; } pk;
                    pk.h[0] = (_Float16)v;
                    pk.h[1] = (_Float16)vp;
                    int cl = (hcol >> 3) ^ (hrow & 7);
                    *(unsigned*)(Hs + ((size_t)hrow * 8 + cl) * 8 + (hcol & 7)) = pk.u;
                }
            }
        __syncthreads();    // drains W2[ncg]; Hs visible
        if (nc < 5) {       // prefetch W1[nc+1] during gemm2
            #pragma unroll
            for (int i = 0; i < 6; i++) {
                int s = (wave * 6 + i) * 64 + lane;
                int rr = s / 24, c = s % 24;
                GLD16(w1 + ((size_t)e * 384 + (nc + 1) * 64 + rr) * 192 + (c ^ (rr & 7)) * 8,
                      (char*)W1s + (size_t)(wave * 6 + i) * 1024);
            }
        }
        // gemm2: this wave's 16 rows x all 192 out-cols, K=64
        #pragma unroll
        for (int kk = 0; kk < 2; kk++) {
            int ar = wr + lr;
            int ch = kk * 4 + quad;
            half8 ha = *(const half8*)(Hs + ((size_t)ar * 8 + (ch ^ (ar & 7))) * 8);
            #pragma unroll
            for (int tj = 0; tj < 12; tj++) {
                int cr = tj * 16 + lr;
                half8 w = *(const half8*)(W2s + ((size_t)cr * 8 + (ch ^ (cr & 7))) * 8);
                acc2[tj] = MFMA_F16(ha, w, acc2[tj], 0, 0, 0);
            }
        }
        __syncthreads();    // drains W1 prefetch
    }

    float sc = scale[0];
    #pragma unroll
    for (int tj = 0; tj < 12; tj++) {
        int gcol = tj * 16 + lr;
        float b2v = b2[e * 192 + gcol];
        #pragma unroll
        for (int r = 0; r < 4; r++) {
            if (rvr[r] >= 0) {
                float v = sc * (acc2[tj][r] + bwr[r] * b2v);
                atomicAdd(&t[(size_t)(rvr[r] >> 1) * DD + gcol], v);
            }
        }
    }
}

// ---------------- banded attention v2: all-thread score phase, float2 LDS -------------
// (correctness-verified in r6/r7 with baseline-identical absmax; -45us vs v1)
__global__ __launch_bounds__(256) void attn_kernel(
    const _Float16* __restrict__ qkv, const float* __restrict__ temp,
    _Float16* __restrict__ o)
{
    __shared__ float q[65][66], k[65][66], v[65][66];
    __shared__ float p[65][9];
    int bh = blockIdx.x;
    int b = bh / 3, h = bh % 3;
    int tid = threadIdx.x;
    float coef = 0.125f / temp[h];
    const _Float16* base = qkv + (size_t)b * 65 * 576 + h * 64;
    for (int idx = tid; idx < 65 * 32; idx += 256) {
        int i = idx >> 5, d2 = (idx & 31) * 2;
        const _Float16* bp = base + (size_t)i * 576 + d2;
        q[i][d2] = (float)bp[0];   q[i][d2 + 1] = (float)bp[1];
        k[i][d2] = (float)bp[192]; k[i][d2 + 1] = (float)bp[193];
        v[i][d2] = (float)bp[384]; v[i][d2 + 1] = (float)bp[385];
    }
    __syncthreads();
    // scores: 455 (i,jo) work items spread over all 256 threads
    for (int idx = tid; idx < 65 * 7; idx += 256) {
        int i = idx / 7, jo = idx % 7;
        int j = i - 3 + jo;
        float s = -1e30f;
        if (j >= 0 && j < 65) {
            const float2* qr = (const float2*)&q[i][0];
            const float2* kr = (const float2*)&k[j][0];
            float acc = 0.f;
            #pragma unroll
            for (int d2 = 0; d2 < 32; d2++) {
                float2 aa = qr[d2], bb = kr[d2];
                acc += aa.x * bb.x + aa.y * bb.y;
            }
            s = acc * coef;
        }
        p[i][jo] = s;
    }
    __syncthreads();
    if (tid < 65) {
        float mx = -1e30f;
        #pragma unroll
        for (int jo = 0; jo < 7; jo++) mx = fmaxf(mx, p[tid][jo]);
        float ex[7], sum = 0.f;
        #pragma unroll
        for (int jo = 0; jo < 7; jo++) { ex[jo] = expf(p[tid][jo] - mx); sum += ex[jo]; }
        float inv = 1.0f / sum;
        #pragma unroll
        for (int jo = 0; jo < 7; jo++) p[tid][jo] = ex[jo] * inv;
    }
    __syncthreads();
    for (int idx = tid; idx < 65 * 32; idx += 256) {
        int i = idx >> 5, d2 = (idx & 31) * 2;
        float s0 = 0.f, s1 = 0.f;
        #pragma unroll
        for (int jo = 0; jo < 7; jo++) {
            int j = i - 3 + jo;
            if (j >= 0 && j < 65) {
                float pv = p[i][jo];
                s0 += pv * v[j][d2];
                s1 += pv * v[j][d2 + 1];
            }
        }
        union { _Float16 h2[2]; unsigned u; } pk;
        pk.h2[0] = (_Float16)s0; pk.h2[1] = (_Float16)s1;
        *(unsigned*)(o + ((size_t)b * 65 + i) * 192 + h * 64 + d2) = pk.u;
    }
}

// ---------------- hyper head (fp32) ----------------
__global__ __launch_bounds__(128) void head_kernel(
    const float* __restrict__ cls, const float* __restrict__ hc_w,
    const float* __restrict__ hc_b, const float* __restrict__ head_w,
    const float* __restrict__ head_b, float* __restrict__ out)
{
    __shared__ float c[192];
    __shared__ float hh[384];
    int b = blockIdx.x, tid = threadIdx.x;
    for (int i = tid; i < 192; i += 128) c[i] = cls[(size_t)b * 192 + i];
    __syncthreads();
    for (int i = tid; i < 384; i += 128) {
        int kx = i / 96, o = i % 96;
        float s = hc_b[i];
        #pragma unroll
        for (int j = 0; j < 4; j++) {
            int pp = (kx - j + 4) & 3;
            const float* w = hc_w + ((size_t)pp * 96 + o) * 48;
            const float* xv = c + j * 48;
            #pragma unroll
            for (int cc = 0; cc < 48; cc++) s += xv[cc] * w[cc];
        }
        hh[i] = gelu_f(s);
    }
    __syncthreads();
    for (int i = tid; i < 100; i += 128) {
        float s = head_b[i];
        const float* w = head_w + (size_t)i * 384;
        for (int kk = 0; kk < 384; kk++) s += hh[kk] * w[kk];
        out[(size_t)b * 100 + i] = s;
    }
}

extern "C" void kernel_launch(void* const* d_in, const int* in_sizes, int n_in,
                              void* d_out, int out_size, void* d_ws, size_t ws_size,
                              hipStream_t stream)
{
    const float* x        = (const float*)d_in[0];
    const float* conv_w   = (const float*)d_in[1];
    const float* conv_b   = (const float*)d_in[2];
    const float* pe_g     = (const float*)d_in[3];
    const float* pe_b     = (const float*)d_in[4];
    const float* cls_tok  = (const float*)d_in[5];
    const float* pos      = (const float*)d_in[6];
    const float* n1_g     = (const float*)d_in[7];
    const float* n1_b     = (const float*)d_in[8];
    const float* qkv_w    = (const float*)d_in[9];
    const float* temp     = (const float*)d_in[10];
    const float* proj_w   = (const float*)d_in[11];
    const float* proj_b   = (const float*)d_in[12];
    const float* n2_g     = (const float*)d_in[13];
    const float* n2_b     = (const float*)d_in[14];
    const float* gate_w   = (const float*)d_in[15];
    const float* gate_b   = (const float*)d_in[16];
    const float* e_w1     = (const float*)d_in[17];
    const float* e_b1     = (const float*)d_in[18];
    const float* e_w2     = (const float*)d_in[19];
    const float* e_b2     = (const float*)d_in[20];
    const float* attn_sc  = (const float*)d_in[21];
    const float* mlp_sc   = (const float*)d_in[22];
    const float* norm_g   = (const float*)d_in[23];
    const float* norm_b   = (const float*)d_in[24];
    const float* hc_w     = (const float*)d_in[25];
    const float* hc_b     = (const float*)d_in[26];
    const float* head_w   = (const float*)d_in[27];
    const float* head_b   = (const float*)d_in[28];

    // ---- ws layout ----
    char* base = (char*)d_ws;
    float*  t     = (float*)base;   base += (size_t)ROWS * DD * 4;        // 6.39MB
    int4*   gwrow = (int4*)base;    base += (size_t)ROWS * 16;            // 133KB
    int*    cnts  = (int*)base;     base += (size_t)12 * 4 * sizeof(int) + 64;
    int*    elist = (int*)base;     base += (size_t)4 * ROWS * 4;         // 133KB
    float*  ewls  = (float*)base;   base += (size_t)4 * ROWS * 4;         // 133KB
    float*  ycls  = (float*)base;   base += (size_t)128 * DD * 4;         // 98KB
    _Float16* yhb = (_Float16*)base; base += (size_t)ROWS * DD * 2;       // 3.19MB
    _Float16* qkvh = (_Float16*)base; base += (size_t)ROWS * 576 * 2;     // 9.58MB
    _Float16* osph = (_Float16*)base; base += (size_t)ROWS * DD * 2;      // 3.19MB
    _Float16* qkvw_h = (_Float16*)base; base += (size_t)12 * 576 * 192 * 2;  // 2.65MB
    _Float16* projw_h = (_Float16*)base; base += (size_t)12 * 192 * 192 * 2; // 0.88MB
    _Float16* ew1_h = (_Float16*)base; base += (size_t)12 * 1536 * 192 * 2;  // 7.1MB
    _Float16* ew2_h = (_Float16*)base; base += (size_t)12 * 192 * 1536 * 2;  // 7.1MB

    hipMemsetAsync(cnts, 0, 12 * 4 * sizeof(int), stream);

    // ---- all weight conversions, one launch ----
    {
        long total = (long)12 * 576 * 192 / 8 + (long)12 * 192 * 192 / 8
                   + (long)12 * 1536 * 192 / 8 + (long)12 * 192 * 192;
        cvt_all_kernel<<<(int)((total + 255) / 256), 256, 0, stream>>>(
            qkv_w, proj_w, e_w1, e_w2, qkvw_h, projw_h, ew1_h, ew2_h);
    }

    embed_kernel<<<128 * 65, 192, 0, stream>>>(x, conv_w, conv_b, pe_g, pe_b, cls_tok, pos, t);

    for (int l = 0; l < 12; l++) {
        ln_kernel<<<ROWS / 4, 256, 0, stream>>>(
            t, nullptr, yhb, n1_g + l * DD, n1_b + l * DD, DD, ROWS,
            nullptr, nullptr, nullptr);
        gemm_h<0><<<dim3(130, 9), 256, 0, stream>>>(
            yhb, qkvw_h + (size_t)l * 576 * 192, 576, qkvh, nullptr, nullptr, nullptr);
        attn_kernel<<<128 * 3, 256, 0, stream>>>(qkvh, temp + l * 3, osph);
        gemm_h<2><<<dim3(130, 3), 256, 0, stream>>>(
            osph, projw_h + (size_t)l * 192 * 192, 192, nullptr, t,
            proj_b + l * DD, attn_sc + l);
        ln_kernel<<<ROWS / 4, 256, 0, stream>>>(
            t, nullptr, yhb, n2_g + l * DD, n2_b + l * DD, DD, ROWS,
            gate_w + (size_t)l * 4 * DD, gate_b + l * 4, gwrow);
        gate_build_kernel<<<(ROWS + 255) / 256, 256, 0, stream>>>(
            gwrow, cnts + l * 4, elist, ewls, ROWS);
        moe_kernel<<<dim3(130, 4), 256, 0, stream>>>(
            yhb, ew1_h + (size_t)l * 1536 * 192, ew2_h + (size_t)l * 192 * 1536,
            e_b1 + (size_t)l * 1536, e_b2 + (size_t)l * 4 * 192, mlp_sc + l,
            cnts + l * 4, elist, ewls, t);
    }

    ln_kernel<<<32, 256, 0, stream>>>(
        t, ycls, nullptr, norm_g, norm_b, (long)65 * DD, 128,
        nullptr, nullptr, nullptr);
    head_kernel<<<128, 128, 0, stream>>>(ycls, hc_w, hc_b, head_w, head_b, (float*)d_out);
}

// Round 10
// 1089.190 us; speedup vs baseline: 1.4158x; 1.1835x over previous
//
#include <hip/hip_runtime.h>
#include <cmath>

// Shapes: B=128, D=192, DEPTH=12, H=3(hd=64), E=4, N=65(tokens), NC=100, WIN_HALF=3
#define ROWS 8320
#define DD   192

typedef __attribute__((ext_vector_type(8))) _Float16 half8;
typedef __attribute__((ext_vector_type(4))) float floatx4;

#define GLD16(gp, lp) __builtin_amdgcn_global_load_lds( \
    (const __attribute__((address_space(1))) void*)(gp), \
    (__attribute__((address_space(3))) void*)(lp), 16, 0, 0)

#define MFMA_F16 __builtin_amdgcn_mfma_f32_16x16x32_f16

// exact gelu ONLY. (r2-r5): the top-2 expert gate flips on ~1e-4 systematic activation
// shifts (tanh-gelu approx -> 9.5e-2 discrete output error). Do NOT approximate.
// (r8): weight fragments must go through coalesced GLD16->LDS staging; per-lane
// column-strided global reads fan out to 64 cache lines/instruction (43->72us).
// (r9): 64-row moe blocks expose the per-block drain chain (260 blocks ~ 1/CU); the
// 32-row/520-block form is the measured optimum of this structure (~42us, 117 TF --
// same effective rate as every other GEMM here; skinny K=192 shapes are latency-bound).
__device__ __forceinline__ float gelu_f(float x) {
    return 0.5f * x * (1.0f + erff(x * 0.70710678118654752440f));
}

// block-wide sum for blockDim.x == 192 (embed only)
__device__ __forceinline__ float blk_sum_192(float v, float* sbuf) {
    int tid = threadIdx.x;
    sbuf[tid] = v;
    __syncthreads();
    for (int off = 96; off >= 3; off >>= 1) {
        if (tid < off) sbuf[tid] += sbuf[tid + off];
        __syncthreads();
    }
    float r = sbuf[0] + sbuf[1] + sbuf[2];
    __syncthreads();
    return r;
}

// ---------------- all weight conversions in ONE launch (data-identical to split) ------
__device__ __forceinline__ void cvt8(const float* __restrict__ sp, _Float16* __restrict__ dp) {
    #pragma unroll
    for (int j = 0; j < 8; j++) dp[j] = (_Float16)sp[j];
}

__global__ __launch_bounds__(256) void cvt_all_kernel(
    const float* __restrict__ qkv_w, const float* __restrict__ proj_w,
    const float* __restrict__ e_w1, const float* __restrict__ e_w2,
    _Float16* __restrict__ qkvw_h, _Float16* __restrict__ projw_h,
    _Float16* __restrict__ ew1_h, _Float16* __restrict__ ew2_h)
{
    long i = (long)blockIdx.x * 256 + threadIdx.x;
    const long n_qkv  = (long)12 * 576 * 192 / 8;    // 165888
    const long n_proj = (long)12 * 192 * 192 / 8;    // 55296
    const long n_w1   = (long)12 * 1536 * 192 / 8;   // 442368
    const long n_w2   = (long)12 * 192 * 192;        // 442368 perm items
    if (i < n_qkv) { cvt8(qkv_w + i * 8, qkvw_h + i * 8); return; }
    i -= n_qkv;
    if (i < n_proj) { cvt8(proj_w + i * 8, projw_h + i * 8); return; }
    i -= n_proj;
    if (i < n_w1) { cvt8(e_w1 + i * 8, ew1_h + i * 8); return; }
    i -= n_w1;
    if (i < n_w2) {
        // e_w2 (12,4,192,384) -> fp16 cat layout [l][n][K'=1536], col = e*384+k
        int l = (int)(i / (192 * 192));
        int rem = (int)(i % (192 * 192));
        int n = rem / 192, p = rem % 192;
        int c0 = p * 8;
        int e = c0 / 384, k0 = c0 % 384;
        cvt8(e_w2 + (((size_t)l * 4 + e) * 192 + n) * 384 + k0, ew2_h + i * 8);
    }
}

// ---------------- patch embed + LN + cls + pos (fp32) ----------------
__global__ __launch_bounds__(192) void embed_kernel(
    const float* __restrict__ x, const float* __restrict__ conv_w,
    const float* __restrict__ conv_b, const float* __restrict__ pe_g,
    const float* __restrict__ pe_b, const float* __restrict__ cls_tok,
    const float* __restrict__ pos, float* __restrict__ t)
{
    __shared__ float patch[48];
    __shared__ float red[192];
    int blk = blockIdx.x;
    int b = blk / 65, n = blk % 65;
    int tid = threadIdx.x;
    if (n == 0) {
        t[(size_t)b * 65 * DD + tid] = cls_tok[tid] + pos[tid];
        return;
    }
    int p = n - 1, gy = p / 8, gx = p % 8;
    if (tid < 48) {
        int c = tid / 16, iy = (tid % 16) / 4, ix = tid % 4;
        patch[tid] = x[((size_t)b * 3 + c) * 1024 + (size_t)(gy * 4 + iy) * 32 + (gx * 4 + ix)];
    }
    __syncthreads();
    float s = conv_b[tid];
    const float* w = conv_w + (size_t)tid * 48;
    #pragma unroll
    for (int f = 0; f < 48; f++) s += patch[f] * w[f];
    float mean = blk_sum_192(s, red) * (1.0f / 192.0f);
    float d = s - mean;
    float var = blk_sum_192(d * d, red) * (1.0f / 192.0f);
    float o = d * rsqrtf(var + 1e-5f) * pe_g[tid] + pe_b[tid];
    t[((size_t)b * 65 + n) * DD + tid] = o + pos[(size_t)n * DD + tid];
}

// ---------------- LayerNorm, wave-per-row (4 rows/block, shuffle-only) ----------------
__global__ __launch_bounds__(256) void ln_kernel(
    const float* __restrict__ in,
    float* __restrict__ yf, _Float16* __restrict__ yh,
    const float* __restrict__ g, const float* __restrict__ bb, long in_stride, int nrows,
    const float* __restrict__ gwm, const float* __restrict__ gb,
    int4* __restrict__ gwout)
{
    int wave = threadIdx.x >> 6, lane = threadIdx.x & 63;
    int r = blockIdx.x * 4 + wave;
    if (r >= nrows) return;
    const float* row = in + (size_t)r * in_stride;
    float v0 = row[lane], v1 = row[lane + 64], v2 = row[lane + 128];
    float s = v0 + v1 + v2;
    #pragma unroll
    for (int off = 32; off > 0; off >>= 1) s += __shfl_xor(s, off);
    float mean = s * (1.0f / 192.0f);
    float d0 = v0 - mean, d1 = v1 - mean, d2 = v2 - mean;
    float q = d0 * d0 + d1 * d1 + d2 * d2;
    #pragma unroll
    for (int off = 32; off > 0; off >>= 1) q += __shfl_xor(q, off);
    float rstd = rsqrtf(q * (1.0f / 192.0f) + 1e-5f);
    float o0 = d0 * rstd * g[lane] + bb[lane];
    float o1 = d1 * rstd * g[lane + 64] + bb[lane + 64];
    float o2 = d2 * rstd * g[lane + 128] + bb[lane + 128];
    if (yf) {
        float* yr = yf + (size_t)r * DD;
        yr[lane] = o0; yr[lane + 64] = o1; yr[lane + 128] = o2;
    }
    if (yh) {
        _Float16* yr = yh + (size_t)r * DD;
        yr[lane] = (_Float16)o0; yr[lane + 64] = (_Float16)o1; yr[lane + 128] = (_Float16)o2;
    }
    if (gwm) {
        float pe[4];
        #pragma unroll
        for (int e = 0; e < 4; e++) {
            const float* w = gwm + (size_t)e * DD;
            pe[e] = o0 * w[lane] + o1 * w[lane + 64] + o2 * w[lane + 128];
            #pragma unroll
            for (int off = 32; off > 0; off >>= 1) pe[e] += __shfl_xor(pe[e], off);
        }
        if (lane == 0) {
            #pragma unroll
            for (int e = 0; e < 4; e++) pe[e] += gb[e];
            float mx = fmaxf(fmaxf(pe[0], pe[1]), fmaxf(pe[2], pe[3]));
            float ex[4];
            #pragma unroll
            for (int e = 0; e < 4; e++) ex[e] = expf(pe[e] - mx);
            int i0 = 0;
            #pragma unroll
            for (int e = 1; e < 4; e++) if (ex[e] > ex[i0]) i0 = e;
            int i1 = (i0 == 0) ? 1 : 0;
            #pragma unroll
            for (int e = 0; e < 4; e++) if (e != i0 && ex[e] > ex[i1]) i1 = e;
            float denom = ex[i0] + ex[i1];
            int4 o4;
            o4.x = i0; o4.y = i1;
            o4.z = __float_as_int(ex[i0] / denom);
            o4.w = __float_as_int(ex[i1] / denom);
            gwout[r] = o4;
        }
    }
}

// ---------------- build per-expert row lists; entry = (row<<1)|rank ----------------
__global__ __launch_bounds__(256) void gate_build_kernel(
    const int4* __restrict__ gwrow, int* __restrict__ cnt,
    int* __restrict__ list, float* __restrict__ wlist, int rows)
{
    int r = blockIdx.x * 256 + threadIdx.x;
    int lane = threadIdx.x & 63;
    bool active = r < rows;
    int4 gv = active ? gwrow[r] : int4{-1, -1, 0, 0};
    #pragma unroll
    for (int e = 0; e < 4; e++) {
        bool sel = active && (gv.x == e || gv.y == e);
        int rank = (gv.x == e) ? 0 : 1;
        float w = (gv.x == e) ? __int_as_float(gv.z) : __int_as_float(gv.w);
        unsigned long long mask = __ballot(sel);
        int cw = __popcll(mask);
        if (cw) {
            int leader = __ffsll((long long)mask) - 1;
            int base = 0;
            if (lane == leader) base = atomicAdd(&cnt[e], cw);
            base = __shfl(base, leader);
            if (sel) {
                int idx = base + __popcll(mask & ((1ULL << lane) - 1ULL));
                list[(size_t)e * ROWS + idx] = (r << 1) | rank;
                wlist[(size_t)e * ROWS + idx] = w;
            }
        }
    }
}

// ---------------- fp16 MFMA GEMM, K=192 (round-1 verified dual-LDS form) --------------
// MODE 0: out fp16 packed [M][Nn]   (qkv; no bias)
// MODE 2: t[r*192+n] += scale[0]*(acc + bias[n])   (proj)
template <int MODE>
__global__ __launch_bounds__(256) void gemm_h(
    const _Float16* __restrict__ A, const _Float16* __restrict__ W,
    int Nn, _Float16* __restrict__ outH, float* __restrict__ t,
    const float* __restrict__ bias, const float* __restrict__ scale)
{
    __shared__ __align__(16) _Float16 As[64 * 192];   // 24KB
    __shared__ __align__(16) _Float16 Ws[64 * 192];   // 24KB
    const int tid = threadIdx.x;
    const int lane = tid & 63, wave = tid >> 6;
    const int m0 = blockIdx.x * 64, n0 = blockIdx.y * 64;
    const int wm = (wave & 1) * 32, wn = (wave >> 1) * 32;
    const int lr = lane & 15, quad = lane >> 4;

    #pragma unroll
    for (int i = 0; i < 6; i++) {
        int s = (wave * 6 + i) * 64 + lane;
        int rr = s / 24, c = s % 24;
        GLD16(A + (size_t)(m0 + rr) * 192 + (c ^ (rr & 7)) * 8,
              (char*)As + (size_t)(wave * 6 + i) * 1024);
        GLD16(W + (size_t)(n0 + rr) * 192 + (c ^ (rr & 7)) * 8,
              (char*)Ws + (size_t)(wave * 6 + i) * 1024);
    }
    __syncthreads();

    floatx4 zero = {0.f, 0.f, 0.f, 0.f};
    floatx4 acc[2][2];
    acc[0][0] = zero; acc[0][1] = zero; acc[1][0] = zero; acc[1][1] = zero;

    #pragma unroll
    for (int m = 0; m < 6; m++) {
        int ch = m * 4 + quad;
        half8 a[2], w[2];
        #pragma unroll
        for (int ti = 0; ti < 2; ti++) {
            int ar = wm + ti * 16 + lr;
            a[ti] = *(const half8*)(As + ((size_t)ar * 24 + (ch ^ (ar & 7))) * 8);
            int cr = wn + ti * 16 + lr;
            w[ti] = *(const half8*)(Ws + ((size_t)cr * 24 + (ch ^ (cr & 7))) * 8);
        }
        #pragma unroll
        for (int ti = 0; ti < 2; ti++)
            #pragma unroll
            for (int tj = 0; tj < 2; tj++)
                acc[ti][tj] = MFMA_F16(a[ti], w[tj], acc[ti][tj], 0, 0, 0);
    }

    float sc = (MODE == 2) ? scale[0] : 0.f;
    #pragma unroll
    for (int ti = 0; ti < 2; ti++)
        #pragma unroll
        for (int tj = 0; tj < 2; tj++)
            #pragma unroll
            for (int r = 0; r < 4; r++) {
                int grow = m0 + wm + ti * 16 + quad * 4 + r;
                int gcol = n0 + wn + tj * 16 + lr;
                float v = acc[ti][tj][r];
                if (MODE == 0) {
                    float vp = __shfl_xor(v, 1);
                    if ((lane & 1) == 0) {
                        union { _Float16 h[2]; unsigned u; } pk;
                        pk.h[0] = (_Float16)v;
                        pk.h[1] = (_Float16)vp;
                        *(unsigned*)(outH + (size_t)grow * Nn + (gcol & ~1)) = pk.u;
                    }
                } else {
                    t[(size_t)grow * DD + gcol] += sc * (v + bias[gcol]);
                }
            }
}

// ---------------- fused MoE (verified optimum: 32 rows/block, LDS-staged) -------------
// grid (260, 4): block = 32 gathered rows of expert e. 6 iters of 64 h-cols.
// Measured ~42us/dispatch = 117 TF effective (same rate as the dense gemms here).
// Tried and lost: z-split (+atomics), direct-reg weights (64-line fanout), 64-row blocks
// (drain exposure). This is the structure's optimum at source level.
__global__ __launch_bounds__(256) void moe_kernel(
    const _Float16* __restrict__ yh, const _Float16* __restrict__ w1,
    const _Float16* __restrict__ w2, const float* __restrict__ b1,
    const float* __restrict__ b2, const float* __restrict__ scale,
    const int* __restrict__ cnt, const int* __restrict__ list,
    const float* __restrict__ wlist, float* __restrict__ t)
{
    __shared__ __align__(16) _Float16 W1s[64 * 192];  // 24KB
    __shared__ __align__(16) _Float16 W2s[192 * 64];  // 24KB
    __shared__ __align__(16) _Float16 Hs[32 * 64];    // 4KB
    const int e  = blockIdx.y;
    const int cnte = cnt[e];
    const int r0 = blockIdx.x * 32;
    if (r0 >= cnte) return;
    const int tid = threadIdx.x;
    const int lane = tid & 63, wave = tid >> 6;
    const int lr = lane & 15, quad = lane >> 4;
    const int wr = (wave & 1) * 16;
    const int wc1 = (wave >> 1) * 16;
    const int wc2 = (wave >> 1) * 96;

    // issue W1 chunk0 staging first (no dependencies)
    #pragma unroll
    for (int i = 0; i < 6; i++) {
        int s = (wave * 6 + i) * 64 + lane;
        int rr = s / 24, c = s % 24;
        GLD16(w1 + ((size_t)e * 384 + rr) * 192 + (c ^ (rr & 7)) * 8,
              (char*)W1s + (size_t)(wave * 6 + i) * 1024);
    }

    // per-lane gather-list entry (lanes 16..63 replicate lanes 0..15's rows)
    int sl = r0 + wr + lr;
    int rv = -1; float wv = 0.f;
    if (sl < cnte) {
        rv = list[(size_t)e * ROWS + sl];
        wv = wlist[(size_t)e * ROWS + sl];
    }
    int arow = (rv >= 0) ? (rv >> 1) : 0;

    // A fragments straight to registers: row arow, chunk ch = m*4+quad
    half8 a[6];
    {
        const _Float16* ap = yh + (size_t)arow * 192 + quad * 8;
        #pragma unroll
        for (int m = 0; m < 6; m++) a[m] = *(const half8*)(ap + m * 32);
    }

    // per-output-row metadata (rows wr+quad*4+r handled by this lane's quad)
    int rvr[4]; float bwr[4];
    #pragma unroll
    for (int r = 0; r < 4; r++) {
        rvr[r] = __shfl(rv, quad * 4 + r);
        bwr[r] = __shfl(wv, quad * 4 + r);
    }

    __syncthreads();   // W1[0] resident (vmcnt0 + barrier)

    floatx4 zero = {0.f, 0.f, 0.f, 0.f};
    floatx4 acc2[6];
    #pragma unroll
    for (int j = 0; j < 6; j++) acc2[j] = zero;

    for (int nc = 0; nc < 6; nc++) {
        int ncg = e * 6 + nc;
        // issue W2[ncg] (flies during gemm1)
        #pragma unroll
        for (int i = 0; i < 6; i++) {
            int s = (wave * 6 + i) * 64 + lane;
            int n = s >> 3, c = s & 7;
            GLD16(w2 + (size_t)n * 1536 + (ncg * 8 + (c ^ (n & 7))) * 8,
                  (char*)W2s + (size_t)(wave * 6 + i) * 1024);
        }
        // gemm1: 32 rows x 64 hcols, K=192, A from registers
        floatx4 acc1[2];
        acc1[0] = zero; acc1[1] = zero;
        #pragma unroll
        for (int m = 0; m < 6; m++) {
            int ch = m * 4 + quad;
            #pragma unroll
            for (int tc = 0; tc < 2; tc++) {
                int cr = wc1 + tc * 32 + lr;
                half8 w = *(const half8*)(W1s + ((size_t)cr * 24 + (ch ^ (cr & 7))) * 8);
                acc1[tc] = MFMA_F16(a[m], w, acc1[tc], 0, 0, 0);
            }
        }
        // epilogue: gelu*w -> Hs fp16, packed 32-bit writes (XOR-banked)
        #pragma unroll
        for (int tc = 0; tc < 2; tc++)
            #pragma unroll
            for (int r = 0; r < 4; r++) {
                int hrow = wr + quad * 4 + r;
                int hcol = wc1 + tc * 32 + lr;
                float v = gelu_f(acc1[tc][r] + b1[64 * ncg + hcol]) * bwr[r];
                float vp = __shfl_xor(v, 1);
                if ((lane & 1) == 0) {
                    union { _Float16 h[2]; unsigned u; } pk;
                    pk.h[0] = (_Float16)v;
                    pk.h[1] = (_Float16)vp;
                    int cl = (hcol >> 3) ^ (hrow & 7);
                    *(unsigned*)(Hs + ((size_t)hrow * 8 + cl) * 8 + (hcol & 7)) = pk.u;
                }
            }
        __syncthreads();    // drains W2[ncg]; Hs visible
        if (nc < 5) {       // prefetch W1[nc+1] during gemm2
            #pragma unroll
            for (int i = 0; i < 6; i++) {
                int s = (wave * 6 + i) * 64 + lane;
                int rr = s / 24, c = s % 24;
                GLD16(w1 + ((size_t)e * 384 + (nc + 1) * 64 + rr) * 192 + (c ^ (rr & 7)) * 8,
                      (char*)W1s + (size_t)(wave * 6 + i) * 1024);
            }
        }
        // gemm2: out[32][192] partial, K=64
        #pragma unroll
        for (int kk = 0; kk < 2; kk++) {
            int ar = wr + lr;
            int ch = kk * 4 + quad;
            half8 ha = *(const half8*)(Hs + ((size_t)ar * 8 + (ch ^ (ar & 7))) * 8);
            #pragma unroll
            for (int tj = 0; tj < 6; tj++) {
                int cr = wc2 + tj * 16 + lr;
                half8 w = *(const half8*)(W2s + ((size_t)cr * 8 + (ch ^ (cr & 7))) * 8);
                acc2[tj] = MFMA_F16(ha, w, acc2[tj], 0, 0, 0);
            }
        }
        __syncthreads();    // drains W1 prefetch
    }

    float sc = scale[0];
    #pragma unroll
    for (int tj = 0; tj < 6; tj++) {
        int gcol = wc2 + tj * 16 + lr;
        float b2v = b2[e * 192 + gcol];
        #pragma unroll
        for (int r = 0; r < 4; r++) {
            if (rvr[r] >= 0) {
                float v = sc * (acc2[tj][r] + bwr[r] * b2v);
                atomicAdd(&t[(size_t)(rvr[r] >> 1) * DD + gcol], v);
            }
        }
    }
}

// ---------------- banded attention v2: all-thread score phase, float2 LDS -------------
// (correctness-verified r6/r7 with baseline-identical absmax; -45us vs serial-score v1)
__global__ __launch_bounds__(256) void attn_kernel(
    const _Float16* __restrict__ qkv, const float* __restrict__ temp,
    _Float16* __restrict__ o)
{
    __shared__ float q[65][66], k[65][66], v[65][66];
    __shared__ float p[65][9];
    int bh = blockIdx.x;
    int b = bh / 3, h = bh % 3;
    int tid = threadIdx.x;
    float coef = 0.125f / temp[h];
    const _Float16* base = qkv + (size_t)b * 65 * 576 + h * 64;
    for (int idx = tid; idx < 65 * 32; idx += 256) {
        int i = idx >> 5, d2 = (idx & 31) * 2;
        const _Float16* bp = base + (size_t)i * 576 + d2;
        q[i][d2] = (float)bp[0];   q[i][d2 + 1] = (float)bp[1];
        k[i][d2] = (float)bp[192]; k[i][d2 + 1] = (float)bp[193];
        v[i][d2] = (float)bp[384]; v[i][d2 + 1] = (float)bp[385];
    }
    __syncthreads();
    // scores: 455 (i,jo) work items spread over all 256 threads
    for (int idx = tid; idx < 65 * 7; idx += 256) {
        int i = idx / 7, jo = idx % 7;
        int j = i - 3 + jo;
        float s = -1e30f;
        if (j >= 0 && j < 65) {
            const float2* qr = (const float2*)&q[i][0];
            const float2* kr = (const float2*)&k[j][0];
            float acc = 0.f;
            #pragma unroll
            for (int d2 = 0; d2 < 32; d2++) {
                float2 aa = qr[d2], bb = kr[d2];
                acc += aa.x * bb.x + aa.y * bb.y;
            }
            s = acc * coef;
        }
        p[i][jo] = s;
    }
    __syncthreads();
    if (tid < 65) {
        float mx = -1e30f;
        #pragma unroll
        for (int jo = 0; jo < 7; jo++) mx = fmaxf(mx, p[tid][jo]);
        float ex[7], sum = 0.f;
        #pragma unroll
        for (int jo = 0; jo < 7; jo++) { ex[jo] = expf(p[tid][jo] - mx); sum += ex[jo]; }
        float inv = 1.0f / sum;
        #pragma unroll
        for (int jo = 0; jo < 7; jo++) p[tid][jo] = ex[jo] * inv;
    }
    __syncthreads();
    for (int idx = tid; idx < 65 * 32; idx += 256) {
        int i = idx >> 5, d2 = (idx & 31) * 2;
        float s0 = 0.f, s1 = 0.f;
        #pragma unroll
        for (int jo = 0; jo < 7; jo++) {
            int j = i - 3 + jo;
            if (j >= 0 && j < 65) {
                float pv = p[i][jo];
                s0 += pv * v[j][d2];
                s1 += pv * v[j][d2 + 1];
            }
        }
        union { _Float16 h2[2]; unsigned u; } pk;
        pk.h2[0] = (_Float16)s0; pk.h2[1] = (_Float16)s1;
        *(unsigned*)(o + ((size_t)b * 65 + i) * 192 + h * 64 + d2) = pk.u;
    }
}

// ---------------- hyper head (fp32) ----------------
__global__ __launch_bounds__(128) void head_kernel(
    const float* __restrict__ cls, const float* __restrict__ hc_w,
    const float* __restrict__ hc_b, const float* __restrict__ head_w,
    const float* __restrict__ head_b, float* __restrict__ out)
{
    __shared__ float c[192];
    __shared__ float hh[384];
    int b = blockIdx.x, tid = threadIdx.x;
    for (int i = tid; i < 192; i += 128) c[i] = cls[(size_t)b * 192 + i];
    __syncthreads();
    for (int i = tid; i < 384; i += 128) {
        int kx = i / 96, o = i % 96;
        float s = hc_b[i];
        #pragma unroll
        for (int j = 0; j < 4; j++) {
            int pp = (kx - j + 4) & 3;
            const float* w = hc_w + ((size_t)pp * 96 + o) * 48;
            const float* xv = c + j * 48;
            #pragma unroll
            for (int cc = 0; cc < 48; cc++) s += xv[cc] * w[cc];
        }
        hh[i] = gelu_f(s);
    }
    __syncthreads();
    for (int i = tid; i < 100; i += 128) {
        float s = head_b[i];
        const float* w = head_w + (size_t)i * 384;
        for (int kk = 0; kk < 384; kk++) s += hh[kk] * w[kk];
        out[(size_t)b * 100 + i] = s;
    }
}

extern "C" void kernel_launch(void* const* d_in, const int* in_sizes, int n_in,
                              void* d_out, int out_size, void* d_ws, size_t ws_size,
                              hipStream_t stream)
{
    const float* x        = (const float*)d_in[0];
    const float* conv_w   = (const float*)d_in[1];
    const float* conv_b   = (const float*)d_in[2];
    const float* pe_g     = (const float*)d_in[3];
    const float* pe_b     = (const float*)d_in[4];
    const float* cls_tok  = (const float*)d_in[5];
    const float* pos      = (const float*)d_in[6];
    const float* n1_g     = (const float*)d_in[7];
    const float* n1_b     = (const float*)d_in[8];
    const float* qkv_w    = (const float*)d_in[9];
    const float* temp     = (const float*)d_in[10];
    const float* proj_w   = (const float*)d_in[11];
    const float* proj_b   = (const float*)d_in[12];
    const float* n2_g     = (const float*)d_in[13];
    const float* n2_b     = (const float*)d_in[14];
    const float* gate_w   = (const float*)d_in[15];
    const float* gate_b   = (const float*)d_in[16];
    const float* e_w1     = (const float*)d_in[17];
    const float* e_b1     = (const float*)d_in[18];
    const float* e_w2     = (const float*)d_in[19];
    const float* e_b2     = (const float*)d_in[20];
    const float* attn_sc  = (const float*)d_in[21];
    const float* mlp_sc   = (const float*)d_in[22];
    const float* norm_g   = (const float*)d_in[23];
    const float* norm_b   = (const float*)d_in[24];
    const float* hc_w     = (const float*)d_in[25];
    const float* hc_b     = (const float*)d_in[26];
    const float* head_w   = (const float*)d_in[27];
    const float* head_b   = (const float*)d_in[28];

    // ---- ws layout ----
    char* base = (char*)d_ws;
    float*  t     = (float*)base;   base += (size_t)ROWS * DD * 4;        // 6.39MB
    int4*   gwrow = (int4*)base;    base += (size_t)ROWS * 16;            // 133KB
    int*    cnts  = (int*)base;     base += (size_t)12 * 4 * sizeof(int) + 64;
    int*    elist = (int*)base;     base += (size_t)4 * ROWS * 4;         // 133KB
    float*  ewls  = (float*)base;   base += (size_t)4 * ROWS * 4;         // 133KB
    float*  ycls  = (float*)base;   base += (size_t)128 * DD * 4;         // 98KB
    _Float16* yhb = (_Float16*)base; base += (size_t)ROWS * DD * 2;       // 3.19MB
    _Float16* qkvh = (_Float16*)base; base += (size_t)ROWS * 576 * 2;     // 9.58MB
    _Float16* osph = (_Float16*)base; base += (size_t)ROWS * DD * 2;      // 3.19MB
    _Float16* qkvw_h = (_Float16*)base; base += (size_t)12 * 576 * 192 * 2;  // 2.65MB
    _Float16* projw_h = (_Float16*)base; base += (size_t)12 * 192 * 192 * 2; // 0.88MB
    _Float16* ew1_h = (_Float16*)base; base += (size_t)12 * 1536 * 192 * 2;  // 7.1MB
    _Float16* ew2_h = (_Float16*)base; base += (size_t)12 * 192 * 1536 * 2;  // 7.1MB

    hipMemsetAsync(cnts, 0, 12 * 4 * sizeof(int), stream);

    // ---- all weight conversions, one launch ----
    {
        long total = (long)12 * 576 * 192 / 8 + (long)12 * 192 * 192 / 8
                   + (long)12 * 1536 * 192 / 8 + (long)12 * 192 * 192;
        cvt_all_kernel<<<(int)((total + 255) / 256), 256, 0, stream>>>(
            qkv_w, proj_w, e_w1, e_w2, qkvw_h, projw_h, ew1_h, ew2_h);
    }

    embed_kernel<<<128 * 65, 192, 0, stream>>>(x, conv_w, conv_b, pe_g, pe_b, cls_tok, pos, t);

    for (int l = 0; l < 12; l++) {
        ln_kernel<<<ROWS / 4, 256, 0, stream>>>(
            t, nullptr, yhb, n1_g + l * DD, n1_b + l * DD, DD, ROWS,
            nullptr, nullptr, nullptr);
        gemm_h<0><<<dim3(130, 9), 256, 0, stream>>>(
            yhb, qkvw_h + (size_t)l * 576 * 192, 576, qkvh, nullptr, nullptr, nullptr);
        attn_kernel<<<128 * 3, 256, 0, stream>>>(qkvh, temp + l * 3, osph);
        gemm_h<2><<<dim3(130, 3), 256, 0, stream>>>(
            osph, projw_h + (size_t)l * 192 * 192, 192, nullptr, t,
            proj_b + l * DD, attn_sc + l);
        ln_kernel<<<ROWS / 4, 256, 0, stream>>>(
            t, nullptr, yhb, n2_g + l * DD, n2_b + l * DD, DD, ROWS,
            gate_w + (size_t)l * 4 * DD, gate_b + l * 4, gwrow);
        gate_build_kernel<<<(ROWS + 255) / 256, 256, 0, stream>>>(
            gwrow, cnts + l * 4, elist, ewls, ROWS);
        moe_kernel<<<dim3(260, 4), 256, 0, stream>>>(
            yhb, ew1_h + (size_t)l * 1536 * 192, ew2_h + (size_t)l * 192 * 1536,
            e_b1 + (size_t)l * 1536, e_b2 + (size_t)l * 4 * 192, mlp_sc + l,
            cnts + l * 4, elist, ewls, t);
    }

    ln_kernel<<<32, 256, 0, stream>>>(
        t, ycls, nullptr, norm_g, norm_b, (long)65 * DD, 128,
        nullptr, nullptr, nullptr);
    head_kernel<<<128, 128, 0, stream>>>(ycls, hc_w, hc_b, head_w, head_b, (float*)d_out);
}